// Round 6
// baseline (109.593 us; speedup 1.0000x reference)
//
#include <hip/hip_runtime.h>
#include <hip/hip_bf16.h>
#include <math.h>

// ---------------- problem constants ----------------
#define M 8192
#define N 16384
#define D 64
#define ZC 58.81206612509905f        // 32*log(2*pi), h=1
#define B0 24.0f                     // exp2-domain bias (headroom; u<=0)
#define LOG2E 1.4426950408889634f
#define HL2E 0.7213475204444817f     // 0.5*log2(e)
#define LN2 0.6931471805599453f

#define PCH 32
#define NCHK (N / PCH)               // 512 train cols per block

typedef short v8bf __attribute__((ext_vector_type(8)));   // 8 bf16 (4 VGPRs)
typedef float v16f __attribute__((ext_vector_type(16)));

// ws layout (bytes)
#define B_AU2  0                        // 8192 f32  (32 KB)
#define B_LW2  32768                    // 16384 f32 (64 KB)
#define B_PART 98304                    // 32*8192 f32 (1 MB), [chunk][m]
#define B_TB   1146880                  // 8192*64 bf16 (1 MB)
#define B_TR   2195456                  // 16384*64 bf16 (2 MB)

// Fused prep: blocks 0..255 convert testX -> bf16(log2e*x) + au2;
// blocks 256..767 convert trainX -> bf16 + lw2 = log2(w) - hl2e*r2 + B0.
__global__ __launch_bounds__(256) void gk_prep(const float* __restrict__ testX,
                                               const float* __restrict__ trainX,
                                               const float* __restrict__ sw,
                                               __hip_bfloat16* __restrict__ tb,
                                               __hip_bfloat16* __restrict__ rb,
                                               float* __restrict__ au2,
                                               float* __restrict__ lw2) {
    const int tid = threadIdx.x;
    const int e = tid & 7;
    if (blockIdx.x < M / 32) {
        const int row = blockIdx.x * 32 + (tid >> 3);
        const float4* p = reinterpret_cast<const float4*>(testX + (size_t)row * D + e * 8);
        float4 v0 = p[0], v1 = p[1];
        float t2 = v0.x * v0.x + v0.y * v0.y + v0.z * v0.z + v0.w * v0.w
                 + v1.x * v1.x + v1.y * v1.y + v1.z * v1.z + v1.w * v1.w;
        t2 += __shfl_xor(t2, 1, 64);
        t2 += __shfl_xor(t2, 2, 64);
        t2 += __shfl_xor(t2, 4, 64);
        if (e == 0) au2[row] = -HL2E * t2;
        union { __hip_bfloat16 h[8]; uint4 u; } cv;
        cv.h[0] = __float2bfloat16(v0.x * LOG2E);
        cv.h[1] = __float2bfloat16(v0.y * LOG2E);
        cv.h[2] = __float2bfloat16(v0.z * LOG2E);
        cv.h[3] = __float2bfloat16(v0.w * LOG2E);
        cv.h[4] = __float2bfloat16(v1.x * LOG2E);
        cv.h[5] = __float2bfloat16(v1.y * LOG2E);
        cv.h[6] = __float2bfloat16(v1.z * LOG2E);
        cv.h[7] = __float2bfloat16(v1.w * LOG2E);
        *reinterpret_cast<uint4*>(tb + (size_t)row * D + e * 8) = cv.u;
    } else {
        const int row = (blockIdx.x - M / 32) * 32 + (tid >> 3);
        const float4* p = reinterpret_cast<const float4*>(trainX + (size_t)row * D + e * 8);
        float4 v0 = p[0], v1 = p[1];
        float r2 = v0.x * v0.x + v0.y * v0.y + v0.z * v0.z + v0.w * v0.w
                 + v1.x * v1.x + v1.y * v1.y + v1.z * v1.z + v1.w * v1.w;
        r2 += __shfl_xor(r2, 1, 64);
        r2 += __shfl_xor(r2, 2, 64);
        r2 += __shfl_xor(r2, 4, 64);
        if (e == 0) lw2[row] = __builtin_amdgcn_logf(sw[row]) - HL2E * r2 + B0;
        union { __hip_bfloat16 h[8]; uint4 u; } cv;
        cv.h[0] = __float2bfloat16(v0.x);
        cv.h[1] = __float2bfloat16(v0.y);
        cv.h[2] = __float2bfloat16(v0.z);
        cv.h[3] = __float2bfloat16(v0.w);
        cv.h[4] = __float2bfloat16(v1.x);
        cv.h[5] = __float2bfloat16(v1.y);
        cv.h[6] = __float2bfloat16(v1.z);
        cv.h[7] = __float2bfloat16(v1.w);
        *reinterpret_cast<uint4*>(rb + (size_t)row * D + e * 8) = cv.u;
    }
}

// Main: 128 test rows x 512 train cols per block; BARRIER-FREE streaming
// K-loop: no LDS staging at all -- B fragments are read straight from
// global (L2-resident, each XCD's slice = 256 KB bf16) while A fragments
// and accumulators live in registers. Each wave owns 64 rows x 256 cols
// (2 m-subtiles) so every B fragment feeds 2 MFMAs. Only sync is the
// final cross-lane reduction. Bias lw2 is the MFMA C operand; epilogue
// per element = exp2 + add.
__global__ __launch_bounds__(256, 4) void gk_main(const __hip_bfloat16* __restrict__ ta,
                                                  const __hip_bfloat16* __restrict__ tr,
                                                  const float* __restrict__ lw2,
                                                  float* __restrict__ part) {
    __shared__ float red[128 * 65];   // 33280 B reduction scratch
    const int tid = threadIdx.x;
    const int w = tid >> 6;
    const int lane = tid & 63;
    const int c = lane & 31;
    const int h = lane >> 5;
    const int mhalf = w & 1;       // which 64-row half
    const int chalf = w >> 1;      // which 256-col half

    // XCD swizzle: xcd = bid&7 owns chunks 4x..4x+3 (2048 train rows, 256 KB bf16)
    const int bid = blockIdx.x;
    const int xcd = bid & 7;
    const int j = bid >> 3;
    const int chunk = xcd * 4 + (j & 3);
    const int m0 = (j >> 2) * 128;
    const int n0 = chunk * NCHK;

    // A fragments once per wave (64 rows = 2 m-subtiles), straight from global
    v8bf af[2][4];
    const __hip_bfloat16* ar = ta + (size_t)(m0 + mhalf * 64 + c) * D;
#pragma unroll
    for (int t = 0; t < 4; ++t) {
        af[0][t] = *reinterpret_cast<const v8bf*>(ar + (2 * t + h) * 8);
        af[1][t] = *reinterpret_cast<const v8bf*>(ar + 32 * D + (2 * t + h) * 8);
    }

    float srun[2][16];
#pragma unroll
    for (int ms = 0; ms < 2; ++ms)
#pragma unroll
        for (int r = 0; r < 16; ++r) srun[ms][r] = 0.f;

    for (int jt = 0; jt < 8; ++jt) {   // 8 col-subtiles of 32
        const int nt = n0 + chalf * 256 + jt * 32;
        const float lwv = lw2[nt + c];
        const __hip_bfloat16* br = tr + (size_t)(nt + c) * D;
        v8bf bf[4];
#pragma unroll
        for (int t = 0; t < 4; ++t)
            bf[t] = *reinterpret_cast<const v8bf*>(br + (2 * t + h) * 8);
#pragma unroll
        for (int ms = 0; ms < 2; ++ms) {
            v16f acc;
#pragma unroll
            for (int r = 0; r < 16; ++r) acc[r] = lwv;   // bias = MFMA C operand
#pragma unroll
            for (int t = 0; t < 4; ++t)
                acc = __builtin_amdgcn_mfma_f32_32x32x16_bf16(af[ms][t], bf[t], acc, 0, 0, 0);
#pragma unroll
            for (int r = 0; r < 16; ++r)
                srun[ms][r] += __builtin_amdgcn_exp2f(acc[r]);
        }
    }

    // ---- final reduction: each (row, col-lane-slot) written exactly once ----
#pragma unroll
    for (int ms = 0; ms < 2; ++ms)
#pragma unroll
        for (int r = 0; r < 16; ++r) {
            int row = mhalf * 64 + ms * 32 + (r & 3) + 8 * (r >> 2) + 4 * h;
            red[row * 65 + chalf * 32 + c] = srun[ms][r];
        }
    __syncthreads();
    if (tid < 128) {
        float G = 0.f;
#pragma unroll
        for (int c2 = 0; c2 < 64; ++c2) G += red[tid * 65 + c2];
        part[(size_t)chunk * M + m0 + tid] = G;   // [chunk][m] coalesced
    }
}

__global__ __launch_bounds__(256) void gk_merge(const float* __restrict__ part,
                                                const float* __restrict__ au2,
                                                const float* __restrict__ sw,
                                                float* __restrict__ out) {
    __shared__ float red[256];
    const int tid = threadIdx.x;
    // W = sum(sw), recomputed per block (64 KB, L2-resident, fully parallel)
    float s = 0.f;
    const float4* p4 = reinterpret_cast<const float4*>(sw);
    for (int i = tid; i < N / 4; i += 256) {
        float4 v = p4[i];
        s += v.x + v.y + v.z + v.w;
    }
    red[tid] = s;
    __syncthreads();
    for (int off = 128; off > 0; off >>= 1) {
        if (tid < off) red[tid] += red[tid + off];
        __syncthreads();
    }
    const float W = red[0];

    const int r = blockIdx.x * 256 + tid;
    float G = 0.f;
#pragma unroll
    for (int p = 0; p < PCH; ++p) G += part[(size_t)p * M + r];
    out[r] = LN2 * (au2[r] + __builtin_amdgcn_logf(fmaxf(G, 1e-30f)) - B0
                   - __builtin_amdgcn_logf(W)) - ZC;
}

extern "C" void kernel_launch(void* const* d_in, const int* in_sizes, int n_in,
                              void* d_out, int out_size, void* d_ws, size_t ws_size,
                              hipStream_t stream) {
    const float* testX  = (const float*)d_in[0];   // [8192, 64]
    const float* trainX = (const float*)d_in[1];   // [16384, 64]
    const float* sw     = (const float*)d_in[2];   // [16384]
    float* out = (float*)d_out;                    // [8192]
    char* wsb = (char*)d_ws;

    float* au2  = (float*)(wsb + B_AU2);
    float* lw2  = (float*)(wsb + B_LW2);
    float* part = (float*)(wsb + B_PART);
    __hip_bfloat16* tb = (__hip_bfloat16*)(wsb + B_TB);
    __hip_bfloat16* rb = (__hip_bfloat16*)(wsb + B_TR);

    gk_prep<<<M / 32 + N / 32, 256, 0, stream>>>(testX, trainX, sw, tb, rb, au2, lw2);
    gk_main<<<(M / 128) * PCH, 256, 0, stream>>>(tb, rb, lw2, part);
    gk_merge<<<M / 256, 256, 0, stream>>>(part, au2, sw, out);
}